// Round 1
// baseline (947.411 us; speedup 1.0000x reference)
//
#include <hip/hip_runtime.h>

#define D_IN 16
#define D_H 32
#define D_CAT 48

// H[n][j] = tanh(x[n] . W_in[j] + b_in[j]);  32 threads per node
__global__ void k_h0(const float* __restrict__ x, const float* __restrict__ W_in,
                     const float* __restrict__ b_in, float* __restrict__ H, int N) {
    int t = blockIdx.x * blockDim.x + threadIdx.x;
    int n = t >> 5;
    int j = t & 31;
    if (n >= N) return;
    const float* xr = x + (size_t)n * D_IN;
    const float* wr = W_in + j * D_IN;
    float acc = b_in[j];
#pragma unroll
    for (int i = 0; i < D_IN; ++i) acc += xr[i] * wr[i];
    H[(size_t)n * D_H + j] = tanhf(acc);
}

// Per-node projections:
//   A[n][j] = b_c[j] + sum_i feats[n][i] * (W_c[j][i] - W_c[j][48+i])
//   B[n][j] =          sum_i feats[n][i] *  W_c[j][48+i]
// feats[n] = [H[n][0..31], x[n][0..15]].  One 64-thread block per node.
__global__ void k_ab(const float* __restrict__ H, const float* __restrict__ x,
                     const float* __restrict__ W_c, const float* __restrict__ b_c,
                     float* __restrict__ A, float* __restrict__ B, int N) {
    __shared__ float f[D_CAT];
    int n = blockIdx.x;
    int t = threadIdx.x;  // 0..63
    if (t < D_H) f[t] = H[(size_t)n * D_H + t];
    else if (t < D_CAT) f[t] = x[(size_t)n * D_IN + (t - D_H)];
    __syncthreads();
    int j = t & 31;
    const float* w = W_c + j * (2 * D_CAT);
    if (t < 32) {
        float acc = b_c[j];
#pragma unroll
        for (int i = 0; i < D_CAT; ++i) acc += f[i] * (w[i] - w[D_CAT + i]);
        A[(size_t)n * D_H + j] = acc;
    } else {
        float acc = 0.f;
#pragma unroll
        for (int i = 0; i < D_CAT; ++i) acc += f[i] * w[D_CAT + i];
        B[(size_t)n * D_H + j] = acc;
    }
}

// Per-edge: msg = sigmoid(A[dst] + B[src]); Hacc[dst] += msg.  32 lanes per edge.
__global__ void k_edge(const int* __restrict__ src, const int* __restrict__ dst,
                       const float* __restrict__ A, const float* __restrict__ B,
                       float* __restrict__ Hacc, int E) {
    int t = blockIdx.x * blockDim.x + threadIdx.x;
    int e = t >> 5;
    int k = t & 31;
    if (e >= E) return;
    int d = dst[e];
    int s = src[e];
    float v = A[(size_t)d * D_H + k] + B[(size_t)s * D_H + k];
    float m = 1.f / (1.f + __expf(-v));
    unsafeAtomicAdd(&Hacc[(size_t)d * D_H + k], m);
}

// Column sums of H into S[32] (S pre-zeroed).
__global__ void k_reduce(const float* __restrict__ H, float* __restrict__ S, int N) {
    int k = threadIdx.x & 31;
    int row = threadIdx.x >> 5;               // 0..7
    int node = blockIdx.x * 8 + row;
    int stride = gridDim.x * 8;
    float acc = 0.f;
    for (int n = node; n < N; n += stride) acc += H[(size_t)n * D_H + k];
    __shared__ float red[8][32];
    red[row][k] = acc;
    __syncthreads();
    if (threadIdx.x < 32) {
        float s = 0.f;
#pragma unroll
        for (int r = 0; r < 8; ++r) s += red[r][threadIdx.x];
        unsafeAtomicAdd(&S[threadIdx.x], s);
    }
}

// out = sigmoid(W_out . (S/N) + b_out)
__global__ void k_final(const float* __restrict__ S, const float* __restrict__ W_out,
                        const float* __restrict__ b_out, float* __restrict__ out,
                        float invN) {
    int j = threadIdx.x;  // 0..63
    float v = 0.f;
    if (j < D_H) v = (S[j] * invN) * W_out[j];
#pragma unroll
    for (int off = 32; off > 0; off >>= 1) v += __shfl_down(v, off);
    if (j == 0) out[0] = 1.f / (1.f + __expf(-(v + b_out[0])));
}

extern "C" void kernel_launch(void* const* d_in, const int* in_sizes, int n_in,
                              void* d_out, int out_size, void* d_ws, size_t ws_size,
                              hipStream_t stream) {
    const float* x     = (const float*)d_in[0];
    const int*   ei    = (const int*)d_in[1];
    const float* W_in  = (const float*)d_in[2];
    const float* b_in  = (const float*)d_in[3];
    const float* W_c   = (const float*)d_in[4];
    const float* b_c   = (const float*)d_in[5];
    const float* W_out = (const float*)d_in[6];
    const float* b_out = (const float*)d_in[7];

    const int N = in_sizes[0] / D_IN;
    const int E = in_sizes[1] / 2;
    const int* src = ei;        // edge_index[0]
    const int* dst = ei + E;    // edge_index[1]

    float* H = (float*)d_ws;                    // N*32
    float* A = H + (size_t)N * D_H;             // N*32
    float* B = A + (size_t)N * D_H;             // N*32
    float* S = B + (size_t)N * D_H;             // 32

    float* out = (float*)d_out;

    k_h0<<<(N * 32 + 255) / 256, 256, 0, stream>>>(x, W_in, b_in, H, N);

    for (int it = 0; it < 2; ++it) {
        k_ab<<<N, 64, 0, stream>>>(H, x, W_c, b_c, A, B, N);
        hipMemsetAsync(H, 0, (size_t)N * D_H * sizeof(float), stream);
        k_edge<<<(int)(((size_t)E * 32 + 255) / 256), 256, 0, stream>>>(src, dst, A, B, H, E);
    }

    hipMemsetAsync(S, 0, D_H * sizeof(float), stream);
    k_reduce<<<256, 256, 0, stream>>>(H, S, N);
    k_final<<<1, 64, 0, stream>>>(S, W_out, b_out, out, 1.f / (float)N);
}

// Round 2
// 414.254 us; speedup vs baseline: 2.2870x; 2.2870x over previous
//
#include <hip/hip_runtime.h>

#define D_H 32
#define NREP 32

// Fused input-net + projection for iteration 0.
// One thread per node. Weights are read at wave-uniform indices -> scalar loads.
//   f[0..31]  = tanh(x @ W_in.T + b_in)   (H0, registers only)
//   f[32..47] = x
//   P = f @ W1.T + b_c ; B = f @ W2.T ; A = P - B
// where W1 = W_c[:, :48], W2 = W_c[:, 48:].
__global__ void k_ab0(const float* __restrict__ x, const float* __restrict__ W_in,
                      const float* __restrict__ b_in, const float* __restrict__ W_c,
                      const float* __restrict__ b_c, float* __restrict__ A,
                      float* __restrict__ B, int N) {
    int n = blockIdx.x * blockDim.x + threadIdx.x;
    if (n >= N) return;
    float f[48];
    const float4* xr = (const float4*)(x + (size_t)n * 16);
#pragma unroll
    for (int q = 0; q < 4; ++q) {
        float4 v = xr[q];
        f[32 + 4 * q] = v.x; f[33 + 4 * q] = v.y;
        f[34 + 4 * q] = v.z; f[35 + 4 * q] = v.w;
    }
#pragma unroll
    for (int j = 0; j < 32; ++j) {
        const float* w = W_in + j * 16;
        float acc = b_in[j];
#pragma unroll
        for (int i = 0; i < 16; ++i) acc += f[32 + i] * w[i];
        f[j] = tanhf(acc);
    }
#pragma unroll 4
    for (int j = 0; j < 32; ++j) {
        const float* w = W_c + j * 96;
        float p = b_c[j];
        float bb = 0.f;
#pragma unroll
        for (int i = 0; i < 48; ++i) {
            p  += f[i] * w[i];
            bb += f[i] * w[48 + i];
        }
        A[(size_t)n * D_H + j] = p - bb;
        B[(size_t)n * D_H + j] = bb;
    }
}

// Projection for iteration 1: feats = [H (from edge pass), x].
__global__ void k_ab1(const float* __restrict__ H, const float* __restrict__ x,
                      const float* __restrict__ W_c, const float* __restrict__ b_c,
                      float* __restrict__ A, float* __restrict__ B, int N) {
    int n = blockIdx.x * blockDim.x + threadIdx.x;
    if (n >= N) return;
    float f[48];
    const float4* hr = (const float4*)(H + (size_t)n * D_H);
#pragma unroll
    for (int q = 0; q < 8; ++q) {
        float4 v = hr[q];
        f[4 * q]     = v.x; f[4 * q + 1] = v.y;
        f[4 * q + 2] = v.z; f[4 * q + 3] = v.w;
    }
    const float4* xr = (const float4*)(x + (size_t)n * 16);
#pragma unroll
    for (int q = 0; q < 4; ++q) {
        float4 v = xr[q];
        f[32 + 4 * q] = v.x; f[33 + 4 * q] = v.y;
        f[34 + 4 * q] = v.z; f[35 + 4 * q] = v.w;
    }
#pragma unroll 4
    for (int j = 0; j < 32; ++j) {
        const float* w = W_c + j * 96;
        float p = b_c[j];
        float bb = 0.f;
#pragma unroll
        for (int i = 0; i < 48; ++i) {
            p  += f[i] * w[i];
            bb += f[i] * w[48 + i];
        }
        A[(size_t)n * D_H + j] = p - bb;
        B[(size_t)n * D_H + j] = bb;
    }
}

// Iter-0 edge pass: msg = sigmoid(A[dst] + B[src]); Hacc[dst] += msg.
// 32 lanes per edge; gathers are one 128B line per edge per array.
__global__ void k_edge1(const int* __restrict__ src, const int* __restrict__ dst,
                        const float* __restrict__ A, const float* __restrict__ B,
                        float* __restrict__ Hacc, int E) {
    int t = blockIdx.x * blockDim.x + threadIdx.x;
    int e = t >> 5;
    int k = t & 31;
    if (e >= E) return;
    int d = dst[e];
    int s = src[e];
    float v = A[(size_t)d * D_H + k] + B[(size_t)s * D_H + k];
    float m = 1.f / (1.f + __expf(-v));
    unsafeAtomicAdd(&Hacc[(size_t)d * D_H + k], m);
}

// Iter-1 edge pass fused with the global mean:
// mean_n(H2)[k] * N == sum_e sigmoid(A[dst]+B[src])[k], so reduce directly.
// Per-thread register accumulation -> per-block LDS reduction -> replicated
// atomic lines (NREP) to avoid single-line atomic serialization.
__global__ void k_edge2(const int* __restrict__ src, const int* __restrict__ dst,
                        const float* __restrict__ A, const float* __restrict__ B,
                        float* __restrict__ Srep, int E) {
    int k = threadIdx.x & 31;
    int slot = threadIdx.x >> 5;            // 0..7
    int e0 = blockIdx.x * 8 + slot;
    int stride = gridDim.x * 8;
    float acc = 0.f;
    for (int e = e0; e < E; e += stride) {
        int d = dst[e];
        int s = src[e];
        float v = A[(size_t)d * D_H + k] + B[(size_t)s * D_H + k];
        acc += 1.f / (1.f + __expf(-v));
    }
    __shared__ float red[8][32];
    red[slot][k] = acc;
    __syncthreads();
    if (threadIdx.x < 32) {
        float s = 0.f;
#pragma unroll
        for (int r = 0; r < 8; ++r) s += red[r][threadIdx.x];
        unsafeAtomicAdd(&Srep[(blockIdx.x & (NREP - 1)) * D_H + threadIdx.x], s);
    }
}

// out = sigmoid(W_out . (S/N) + b_out), S = sum over replicas.
__global__ void k_final(const float* __restrict__ Srep, const float* __restrict__ W_out,
                        const float* __restrict__ b_out, float* __restrict__ out,
                        float invN) {
    int j = threadIdx.x;  // 0..63
    float v = 0.f;
    if (j < 32) {
        float s = 0.f;
#pragma unroll
        for (int r = 0; r < NREP; ++r) s += Srep[r * D_H + j];
        v = s * invN * W_out[j];
    }
#pragma unroll
    for (int off = 32; off > 0; off >>= 1) v += __shfl_down(v, off);
    if (j == 0) out[0] = 1.f / (1.f + __expf(-(v + b_out[0])));
}

extern "C" void kernel_launch(void* const* d_in, const int* in_sizes, int n_in,
                              void* d_out, int out_size, void* d_ws, size_t ws_size,
                              hipStream_t stream) {
    const float* x     = (const float*)d_in[0];
    const int*   ei    = (const int*)d_in[1];
    const float* W_in  = (const float*)d_in[2];
    const float* b_in  = (const float*)d_in[3];
    const float* W_c   = (const float*)d_in[4];
    const float* b_c   = (const float*)d_in[5];
    const float* W_out = (const float*)d_in[6];
    const float* b_out = (const float*)d_in[7];

    const int N = in_sizes[0] / 16;
    const int E = in_sizes[1] / 2;
    const int* src = ei;        // edge_index[0]
    const int* dst = ei + E;    // edge_index[1]

    float* H    = (float*)d_ws;                  // N*32
    float* A    = H + (size_t)N * D_H;           // N*32
    float* B    = A + (size_t)N * D_H;           // N*32
    float* Srep = B + (size_t)N * D_H;           // NREP*32

    float* out = (float*)d_out;

    // Iteration 0
    k_ab0<<<(N + 255) / 256, 256, 0, stream>>>(x, W_in, b_in, W_c, b_c, A, B, N);
    hipMemsetAsync(H, 0, (size_t)N * D_H * sizeof(float), stream);
    k_edge1<<<(int)(((size_t)E * 32 + 255) / 256), 256, 0, stream>>>(src, dst, A, B, H, E);

    // Iteration 1 (projection), then fused edge+mean reduction
    k_ab1<<<(N + 255) / 256, 256, 0, stream>>>(H, x, W_c, b_c, A, B, N);
    hipMemsetAsync(Srep, 0, NREP * D_H * sizeof(float), stream);
    k_edge2<<<2048, 256, 0, stream>>>(src, dst, A, B, Srep, E);

    k_final<<<1, 64, 0, stream>>>(Srep, W_out, b_out, out, 1.f / (float)N);
}